// Round 16
// baseline (93.087 us; speedup 1.0000x reference)
//
#include <hip/hip_runtime.h>
#include <hip/hip_bf16.h>
#include <stdint.h>
#include <math.h>

#define SLEN 512
#define NT 48
#define TAG_START 46
#define TAG_STOP 47

typedef __attribute__((ext_vector_type(8))) short bf16x8;
typedef __attribute__((ext_vector_type(4))) float f32x4;

typedef const uint32_t __attribute__((address_space(1)))* gptr_t;
typedef uint32_t __attribute__((address_space(3)))* lptr_t;

__device__ __forceinline__ float bcastf(float v, int l) {
  return __int_as_float(__builtin_amdgcn_readlane(__float_as_int(v), l));
}
__device__ __forceinline__ void gload16(const float* g, float* l) {
  __builtin_amdgcn_global_load_lds((gptr_t)(uintptr_t)g, (lptr_t)(uintptr_t)l,
                                   16, 0, 0);
}
// Truncation pack (R14-proven): lo16=hi16(a), hi16=hi16(b); one v_perm_b32.
__device__ __forceinline__ uint32_t pk2(float a, float b) {
  return __builtin_amdgcn_perm(__float_as_uint(b), __float_as_uint(a),
                               0x07060302u);
}

// shared power-of-2 rescale of 3 f32x4 state regs (data lanes 0/16/32/48)
#define RENORM3(r0, r1, r2)                                                  \
  {                                                                          \
    f32x4 m4_ = __builtin_elementwise_max(                                   \
        __builtin_elementwise_max(r0, r1), r2);                              \
    float mx_ = fmaxf(fmaxf(m4_.x, m4_.y), fmaxf(m4_.z, fmaxf(m4_.w,        \
                                                              1e-30f)));     \
    mx_ = fmaxf(fmaxf(bcastf(mx_, 0), bcastf(mx_, 16)),                      \
                fmaxf(bcastf(mx_, 32), bcastf(mx_, 48)));                    \
    const int ex_ = ((__float_as_int(mx_) >> 23) & 255) - 126;               \
    const float sc_ = __int_as_float((127 - ex_) << 23);                     \
    r0 *= sc_;                                                               \
    r1 *= sc_;                                                               \
    r2 *= sc_;                                                               \
    cbits += ex_;                                                            \
  }

// Load pair s's six x-vectors (pre-exp'd in LDS) into register set SFX.
#define LOADX(SFX, s)                                                        \
  {                                                                          \
    const float* xfp_ = F + (s)*NT;                                          \
    const float* xbp_ = Bw + (31 - (s)) * NT;                                \
    XF0##SFX = *(const f32x4*)(xfp_ + 4 * g);                                \
    XF1##SFX = *(const f32x4*)(xfp_ + 16 + 4 * g);                           \
    XF2##SFX = *(const f32x4*)(xfp_ + 32 + 4 * g);                           \
    XB0##SFX = *(const f32x4*)(xbp_ + 4 * g);                                \
    XB1##SFX = *(const f32x4*)(xbp_ + 16 + 4 * g);                           \
    XB2##SFX = *(const f32x4*)(xbp_ + 32 + 4 * g);                           \
  }

// One wave per batch. Bidirectional meet-in-the-middle, software-pipelined
// (R12/R14 lineage, absmax 0). R15: x prefetched 1 pair ahead in registers.
__global__ __launch_bounds__(64) void crf_fwd_kernel(
    const float* __restrict__ em, const int* __restrict__ tags,
    const int* __restrict__ mask, const float* __restrict__ Tr,
    float* __restrict__ ws) {
  const int b = blockIdx.x;
  const int lane = threadIdx.x;
  const int g = lane >> 4;
  const int n = lane & 15;
  __shared__ __align__(16) float fbuf[2][32 * NT];
  __shared__ __align__(16) float bbuf[2][32 * NT];

  // length = sum(mask row)  (prefix mask)
  const int* mrow = mask + (size_t)b * SLEN;
  int lc = 0;
  for (int t = lane; t < SLEN; t += 64) lc += mrow[t];
#pragma unroll
  for (int d = 32; d >= 1; d >>= 1) lc += __shfl_xor(lc, d);
  const int len = lc;  // uniform; len >= 256

  // A fragments (R8/R10-verified layouts). Fwd rows of E^T; Bwd rows of E.
  bf16x8 Af[3][2], Ab[3][2];
#pragma unroll
  for (int t = 0; t < 3; ++t) {
#pragma unroll
    for (int c = 0; c < 2; ++c) {
      union { uint32_t u[4]; bf16x8 v; } tf, tb;
#pragma unroll
      for (int ep = 0; ep < 4; ++ep) {
        float ff[2], fbk[2];
#pragma unroll
        for (int h = 0; h < 2; ++h) {
          const int e = 2 * ep + h;
          const int kl = (e < 4) ? (4 * g + e) : (16 + 4 * g + (e - 4));
          const int ig = 32 * c + kl;
          ff[h] = (ig < NT) ? __expf(Tr[ig * NT + 16 * t + n]) : 0.0f;
          fbk[h] = (ig < NT) ? __expf(Tr[(16 * t + n) * NT + ig]) : 0.0f;
        }
        tf.u[ep] = pk2(ff[0], ff[1]);
        tb.u[ep] = pk2(fbk[0], fbk[1]);
      }
      Af[t][c] = tf.v;
      Ab[t][c] = tb.v;
    }
  }

  const f32x4 z4 = {0.f, 0.f, 0.f, 0.f};
  int cbits = 0;

  // aA = in-flight E^T q. Init = E^T e_START = exp(T[START, j]) (exact).
  f32x4 aA0 = z4, aA1 = z4, aA2 = z4;
  if (n == 0) {
#define INITA(dst, t)                                             \
  {                                                               \
    f32x4 r_;                                                     \
    r_.x = __expf(Tr[TAG_START * NT + 16 * (t) + 4 * g + 0]);     \
    r_.y = __expf(Tr[TAG_START * NT + 16 * (t) + 4 * g + 1]);     \
    r_.z = __expf(Tr[TAG_START * NT + 16 * (t) + 4 * g + 2]);     \
    r_.w = __expf(Tr[TAG_START * NT + 16 * (t) + 4 * g + 3]);     \
    dst = r_;                                                     \
  }
    INITA(aA0, 0)
    INITA(aA1, 1)
    INITA(aA2, 2)
#undef INITA
  }
  // aB = in-flight w state. Init = w0 = ones (data lanes).
  f32x4 aB0 = z4, aB1 = z4, aB2 = z4;
  if (n == 0) {
    const f32x4 one4 = {1.f, 1.f, 1.f, 1.f};
    aB0 = one4;
    aB1 = one4;
    aB2 = one4;
  }

  f32x4 vf0 = z4, vf1 = z4, vf2 = z4;  // last consumed fwd state
  const float* embase = em + (size_t)b * SLEN * NT;

  auto pairbody = [&](f32x4 xf0, f32x4 xf1, f32x4 xf2, f32x4 xb0, f32x4 xb1,
                      f32x4 xb2, bool rn) {
    // ---- forward half: q' = aA ∘ xf; issue E^T q'
    vf0 = aA0 * xf0;
    vf1 = aA1 * xf1;
    vf2 = aA2 * xf2;
    if (rn) RENORM3(vf0, vf1, vf2);
    union { uint32_t u[4]; bf16x8 v; } F0, F1;
    F0.u[0] = pk2(vf0.x, vf0.y);
    F0.u[1] = pk2(vf0.z, vf0.w);
    F0.u[2] = pk2(vf1.x, vf1.y);
    F0.u[3] = pk2(vf1.z, vf1.w);
    F1.u[0] = pk2(vf2.x, vf2.y);
    F1.u[1] = pk2(vf2.z, vf2.w);
    F1.u[2] = 0u;
    F1.u[3] = 0u;
    aA0 = __builtin_amdgcn_mfma_f32_16x16x32_bf16(Af[0][0], F0.v, z4, 0, 0, 0);
    aA1 = __builtin_amdgcn_mfma_f32_16x16x32_bf16(Af[1][0], F0.v, z4, 0, 0, 0);
    aA2 = __builtin_amdgcn_mfma_f32_16x16x32_bf16(Af[2][0], F0.v, z4, 0, 0, 0);
    aA0 = __builtin_amdgcn_mfma_f32_16x16x32_bf16(Af[0][1], F1.v, aA0, 0, 0, 0);
    aA1 = __builtin_amdgcn_mfma_f32_16x16x32_bf16(Af[1][1], F1.v, aA1, 0, 0, 0);
    aA2 = __builtin_amdgcn_mfma_f32_16x16x32_bf16(Af[2][1], F1.v, aA2, 0, 0, 0);
    // ---- backward half: y = aB ∘ xb; issue E·y
    f32x4 y0 = aB0 * xb0;
    f32x4 y1 = aB1 * xb1;
    f32x4 y2 = aB2 * xb2;
    if (rn) RENORM3(y0, y1, y2);
    union { uint32_t u[4]; bf16x8 v; } G0, G1;
    G0.u[0] = pk2(y0.x, y0.y);
    G0.u[1] = pk2(y0.z, y0.w);
    G0.u[2] = pk2(y1.x, y1.y);
    G0.u[3] = pk2(y1.z, y1.w);
    G1.u[0] = pk2(y2.x, y2.y);
    G1.u[1] = pk2(y2.z, y2.w);
    G1.u[2] = 0u;
    G1.u[3] = 0u;
    aB0 = __builtin_amdgcn_mfma_f32_16x16x32_bf16(Ab[0][0], G0.v, z4, 0, 0, 0);
    aB1 = __builtin_amdgcn_mfma_f32_16x16x32_bf16(Ab[1][0], G0.v, z4, 0, 0, 0);
    aB2 = __builtin_amdgcn_mfma_f32_16x16x32_bf16(Ab[2][0], G0.v, z4, 0, 0, 0);
    aB0 = __builtin_amdgcn_mfma_f32_16x16x32_bf16(Ab[0][1], G1.v, aB0, 0, 0, 0);
    aB1 = __builtin_amdgcn_mfma_f32_16x16x32_bf16(Ab[1][1], G1.v, aB1, 0, 0, 0);
    aB2 = __builtin_amdgcn_mfma_f32_16x16x32_bf16(Ab[2][1], G1.v, aB2, 0, 0, 0);
  };

  const int m = len >> 1;
  const int nwin = (m + 31) >> 5;

  // stage window 0: fwd rows [0,32), bwd rows [len-32, len)
#pragma unroll
  for (int k = 0; k < 6; ++k) {
    gload16(embase + k * 256 + lane * 4, &fbuf[0][k * 256]);
    gload16(embase + (size_t)(len - 32) * NT + k * 256 + lane * 4,
            &bbuf[0][k * 256]);
  }

  for (int c = 0; c < nwin; ++c) {
    asm volatile("s_waitcnt vmcnt(0)" ::: "memory");
    if (c + 1 < nwin) {
      const float* fsrc = embase + (size_t)(32 * (c + 1)) * NT;
      const float* bsrc = embase + (size_t)(len - 32 - 32 * (c + 1)) * NT;
#pragma unroll
      for (int k = 0; k < 6; ++k) {
        gload16(fsrc + k * 256 + lane * 4, &fbuf[(c + 1) & 1][k * 256]);
        gload16(bsrc + k * 256 + lane * 4, &bbuf[(c + 1) & 1][k * 256]);
      }
    }
    float* F = fbuf[c & 1];
    float* Bw = bbuf[c & 1];
#pragma unroll
    for (int r = 0; r < 6; ++r) {  // pre-exp, flat (2-way alias = free)
      f32x4* p = (f32x4*)(F + r * 256 + lane * 4);
      f32x4 vx = *p;
      vx.x = __expf(vx.x);
      vx.y = __expf(vx.y);
      vx.z = __expf(vx.z);
      vx.w = __expf(vx.w);
      *p = vx;
      f32x4* p2 = (f32x4*)(Bw + r * 256 + lane * 4);
      f32x4 vy = *p2;
      vy.x = __expf(vy.x);
      vy.y = __expf(vy.y);
      vy.z = __expf(vy.z);
      vy.w = __expf(vy.w);
      *p2 = vy;
    }
    const int pairs = (m - 32 * c < 32) ? (m - 32 * c) : 32;
    // 1-pair-lookahead register pipeline (named A/B sets, static indexing)
    f32x4 XF0a, XF1a, XF2a, XB0a, XB1a, XB2a;
    f32x4 XF0b, XF1b, XF2b, XB0b, XB1b, XB2b;
    LOADX(a, 0);
    int s = 0;
    for (; s + 2 <= pairs; s += 2) {
      LOADX(b, s + 1);  // prefetch pair s+1 while computing pair s
      pairbody(XF0a, XF1a, XF2a, XB0a, XB1a, XB2a,
               ((s & 7) == 7) || (s == pairs - 1));
      if (s + 2 < pairs) LOADX(a, s + 2);  // prefetch pair s+2
      pairbody(XF0b, XF1b, XF2b, XB0b, XB1b, XB2b,
               (((s + 1) & 7) == 7) || (s + 1 == pairs - 1));
    }
    if (s < pairs)  // odd tail: pair already loaded in A set
      pairbody(XF0a, XF1a, XF2a, XB0a, XB1a, XB2a, true);
  }

  if (len & 1) {  // one extra backward step, row m, direct from global
    const float* rp = embase + (size_t)m * NT;
    f32x4 xb0 = *(const f32x4*)(rp + 4 * g);
    f32x4 xb1 = *(const f32x4*)(rp + 16 + 4 * g);
    f32x4 xb2 = *(const f32x4*)(rp + 32 + 4 * g);
#define EXP4(v) \
  v.x = __expf(v.x); v.y = __expf(v.y); v.z = __expf(v.z); v.w = __expf(v.w)
    EXP4(xb0);
    EXP4(xb1);
    EXP4(xb2);
#undef EXP4
    const f32x4 y0 = aB0 * xb0, y1 = aB1 * xb1, y2 = aB2 * xb2;
    union { uint32_t u[4]; bf16x8 v; } G0, G1;
    G0.u[0] = pk2(y0.x, y0.y);
    G0.u[1] = pk2(y0.z, y0.w);
    G0.u[2] = pk2(y1.x, y1.y);
    G0.u[3] = pk2(y1.z, y1.w);
    G1.u[0] = pk2(y2.x, y2.y);
    G1.u[1] = pk2(y2.z, y2.w);
    G1.u[2] = 0u;
    G1.u[3] = 0u;
    aB0 = __builtin_amdgcn_mfma_f32_16x16x32_bf16(Ab[0][0], G0.v, z4, 0, 0, 0);
    aB1 = __builtin_amdgcn_mfma_f32_16x16x32_bf16(Ab[1][0], G0.v, z4, 0, 0, 0);
    aB2 = __builtin_amdgcn_mfma_f32_16x16x32_bf16(Ab[2][0], G0.v, z4, 0, 0, 0);
    aB0 = __builtin_amdgcn_mfma_f32_16x16x32_bf16(Ab[0][1], G1.v, aB0, 0, 0, 0);
    aB1 = __builtin_amdgcn_mfma_f32_16x16x32_bf16(Ab[1][1], G1.v, aB1, 0, 0, 0);
    aB2 = __builtin_amdgcn_mfma_f32_16x16x32_bf16(Ab[2][1], G1.v, aB2, 0, 0, 0);
  }

  // Z = q_m · w_m. vf = q_m (renormed at last pair); aB = w_m in flight.
  f32x4 dv = vf0 * aB0 + vf1 * aB1 + vf2 * aB2;
  float dsum = (dv.x + dv.y) + (dv.z + dv.w);
#pragma unroll
  for (int d = 32; d >= 1; d >>= 1) dsum += __shfl_xor(dsum, d);
  const float logZ =
      __logf(dsum) + (float)cbits * 0.69314718055994531f + Tr[TAG_STOP * NT];

  // gold score (matched at absmax 0 since R2)
  const int* trow = tags + (size_t)b * SLEN;
  float gsc = 0.f;
  for (int t = lane; t < len; t += 64) {
    const int tag = trow[t];
    const int prev = (t == 0) ? TAG_START : trow[t - 1];
    gsc += Tr[tag * NT + prev] + embase[(size_t)t * NT + tag];
  }
#pragma unroll
  for (int d = 32; d >= 1; d >>= 1) gsc += __shfl_xor(gsc, d);

  if (lane == 0) {
    const int last = trow[len - 1];
    ws[b] = logZ - (gsc + Tr[TAG_STOP * NT + last]);
  }
}

// Deterministic tree-mean over B values (no atomics).
__global__ void crf_reduce_kernel(const float* __restrict__ wsrc,
                                  float* __restrict__ out, int n) {
  const int tid = threadIdx.x;
  float v = (tid < n) ? wsrc[tid] : 0.f;
#pragma unroll
  for (int d = 32; d >= 1; d >>= 1) v += __shfl_xor(v, d);
  __shared__ float part[16];
  if ((tid & 63) == 0) part[tid >> 6] = v;
  __syncthreads();
  if (tid == 0) {
    float s = 0.f;
    for (int i = 0; i < 16; ++i) s += part[i];
    out[0] = s / (float)n;
  }
}

extern "C" void kernel_launch(void* const* d_in, const int* in_sizes, int n_in,
                              void* d_out, int out_size, void* d_ws, size_t ws_size,
                              hipStream_t stream) {
  const float* em = (const float*)d_in[0];
  const int* tags = (const int*)d_in[1];
  const int* mask = (const int*)d_in[2];
  const float* Tr = (const float*)d_in[3];
  const int B = in_sizes[0] / (SLEN * NT);  // 1024

  float* ws = (float*)d_ws;  // B floats
  crf_fwd_kernel<<<B, 64, 0, stream>>>(em, tags, mask, Tr, ws);
  crf_reduce_kernel<<<1, 1024, 0, stream>>>(ws, (float*)d_out, B);
}

// Round 17
// 92.518 us; speedup vs baseline: 1.0061x; 1.0061x over previous
//
#include <hip/hip_runtime.h>
#include <hip/hip_bf16.h>
#include <stdint.h>
#include <math.h>

#define SLEN 512
#define NT 48
#define TAG_START 46
#define TAG_STOP 47

typedef __attribute__((ext_vector_type(8))) short bf16x8;
typedef __attribute__((ext_vector_type(4))) float f32x4;

typedef const uint32_t __attribute__((address_space(1)))* gptr_t;
typedef uint32_t __attribute__((address_space(3)))* lptr_t;

__device__ __forceinline__ float bcastf(float v, int l) {
  return __int_as_float(__builtin_amdgcn_readlane(__float_as_int(v), l));
}
__device__ __forceinline__ void gload16(const float* g, float* l) {
  __builtin_amdgcn_global_load_lds((gptr_t)(uintptr_t)g, (lptr_t)(uintptr_t)l,
                                   16, 0, 0);
}
// Truncation pack (R14-proven): lo16=hi16(a), hi16=hi16(b); one v_perm_b32.
__device__ __forceinline__ uint32_t pk2(float a, float b) {
  return __builtin_amdgcn_perm(__float_as_uint(b), __float_as_uint(a),
                               0x07060302u);
}

// shared power-of-2 rescale of 3 f32x4 state regs (data lanes 0/16/32/48)
#define RENORM3(r0, r1, r2)                                                  \
  {                                                                          \
    f32x4 m4_ = __builtin_elementwise_max(                                   \
        __builtin_elementwise_max(r0, r1), r2);                              \
    float mx_ = fmaxf(fmaxf(m4_.x, m4_.y), fmaxf(m4_.z, fmaxf(m4_.w,        \
                                                              1e-30f)));     \
    mx_ = fmaxf(fmaxf(bcastf(mx_, 0), bcastf(mx_, 16)),                      \
                fmaxf(bcastf(mx_, 32), bcastf(mx_, 48)));                    \
    const int ex_ = ((__float_as_int(mx_) >> 23) & 255) - 126;               \
    const float sc_ = __int_as_float((127 - ex_) << 23);                     \
    r0 *= sc_;                                                               \
    r1 *= sc_;                                                               \
    r2 *= sc_;                                                               \
    cbits += ex_;                                                            \
  }

// Load pair s's six x-vectors (pre-exp'd in LDS) into register set SFX.
#define LOADX(SFX, s)                                                        \
  {                                                                          \
    const float* xfp_ = F + (s)*NT;                                          \
    const float* xbp_ = Bw + (31 - (s)) * NT;                                \
    XF0##SFX = *(const f32x4*)(xfp_ + 4 * g);                                \
    XF1##SFX = *(const f32x4*)(xfp_ + 16 + 4 * g);                           \
    XF2##SFX = *(const f32x4*)(xfp_ + 32 + 4 * g);                           \
    XB0##SFX = *(const f32x4*)(xbp_ + 4 * g);                                \
    XB1##SFX = *(const f32x4*)(xbp_ + 16 + 4 * g);                           \
    XB2##SFX = *(const f32x4*)(xbp_ + 32 + 4 * g);                           \
  }

// One wave per batch. Bidirectional meet-in-the-middle, software-pipelined
// (R12/R14 lineage, absmax 0). R15: x prefetched 1 pair ahead in registers.
__global__ __launch_bounds__(64) void crf_fwd_kernel(
    const float* __restrict__ em, const int* __restrict__ tags,
    const int* __restrict__ mask, const float* __restrict__ Tr,
    float* __restrict__ ws) {
  const int b = blockIdx.x;
  const int lane = threadIdx.x;
  const int g = lane >> 4;
  const int n = lane & 15;
  __shared__ __align__(16) float fbuf[2][32 * NT];
  __shared__ __align__(16) float bbuf[2][32 * NT];

  // length = sum(mask row)  (prefix mask)
  const int* mrow = mask + (size_t)b * SLEN;
  int lc = 0;
  for (int t = lane; t < SLEN; t += 64) lc += mrow[t];
#pragma unroll
  for (int d = 32; d >= 1; d >>= 1) lc += __shfl_xor(lc, d);
  const int len = lc;  // uniform; len >= 256

  // A fragments (R8/R10-verified layouts). Fwd rows of E^T; Bwd rows of E.
  bf16x8 Af[3][2], Ab[3][2];
#pragma unroll
  for (int t = 0; t < 3; ++t) {
#pragma unroll
    for (int c = 0; c < 2; ++c) {
      union { uint32_t u[4]; bf16x8 v; } tf, tb;
#pragma unroll
      for (int ep = 0; ep < 4; ++ep) {
        float ff[2], fbk[2];
#pragma unroll
        for (int h = 0; h < 2; ++h) {
          const int e = 2 * ep + h;
          const int kl = (e < 4) ? (4 * g + e) : (16 + 4 * g + (e - 4));
          const int ig = 32 * c + kl;
          ff[h] = (ig < NT) ? __expf(Tr[ig * NT + 16 * t + n]) : 0.0f;
          fbk[h] = (ig < NT) ? __expf(Tr[(16 * t + n) * NT + ig]) : 0.0f;
        }
        tf.u[ep] = pk2(ff[0], ff[1]);
        tb.u[ep] = pk2(fbk[0], fbk[1]);
      }
      Af[t][c] = tf.v;
      Ab[t][c] = tb.v;
    }
  }

  const f32x4 z4 = {0.f, 0.f, 0.f, 0.f};
  int cbits = 0;

  // aA = in-flight E^T q. Init = E^T e_START = exp(T[START, j]) (exact).
  f32x4 aA0 = z4, aA1 = z4, aA2 = z4;
  if (n == 0) {
#define INITA(dst, t)                                             \
  {                                                               \
    f32x4 r_;                                                     \
    r_.x = __expf(Tr[TAG_START * NT + 16 * (t) + 4 * g + 0]);     \
    r_.y = __expf(Tr[TAG_START * NT + 16 * (t) + 4 * g + 1]);     \
    r_.z = __expf(Tr[TAG_START * NT + 16 * (t) + 4 * g + 2]);     \
    r_.w = __expf(Tr[TAG_START * NT + 16 * (t) + 4 * g + 3]);     \
    dst = r_;                                                     \
  }
    INITA(aA0, 0)
    INITA(aA1, 1)
    INITA(aA2, 2)
#undef INITA
  }
  // aB = in-flight w state. Init = w0 = ones (data lanes).
  f32x4 aB0 = z4, aB1 = z4, aB2 = z4;
  if (n == 0) {
    const f32x4 one4 = {1.f, 1.f, 1.f, 1.f};
    aB0 = one4;
    aB1 = one4;
    aB2 = one4;
  }

  f32x4 vf0 = z4, vf1 = z4, vf2 = z4;  // last consumed fwd state
  const float* embase = em + (size_t)b * SLEN * NT;

  auto pairbody = [&](f32x4 xf0, f32x4 xf1, f32x4 xf2, f32x4 xb0, f32x4 xb1,
                      f32x4 xb2, bool rn) {
    // ---- forward half: q' = aA ∘ xf; issue E^T q'
    vf0 = aA0 * xf0;
    vf1 = aA1 * xf1;
    vf2 = aA2 * xf2;
    if (rn) RENORM3(vf0, vf1, vf2);
    union { uint32_t u[4]; bf16x8 v; } F0, F1;
    F0.u[0] = pk2(vf0.x, vf0.y);
    F0.u[1] = pk2(vf0.z, vf0.w);
    F0.u[2] = pk2(vf1.x, vf1.y);
    F0.u[3] = pk2(vf1.z, vf1.w);
    F1.u[0] = pk2(vf2.x, vf2.y);
    F1.u[1] = pk2(vf2.z, vf2.w);
    F1.u[2] = 0u;
    F1.u[3] = 0u;
    aA0 = __builtin_amdgcn_mfma_f32_16x16x32_bf16(Af[0][0], F0.v, z4, 0, 0, 0);
    aA1 = __builtin_amdgcn_mfma_f32_16x16x32_bf16(Af[1][0], F0.v, z4, 0, 0, 0);
    aA2 = __builtin_amdgcn_mfma_f32_16x16x32_bf16(Af[2][0], F0.v, z4, 0, 0, 0);
    aA0 = __builtin_amdgcn_mfma_f32_16x16x32_bf16(Af[0][1], F1.v, aA0, 0, 0, 0);
    aA1 = __builtin_amdgcn_mfma_f32_16x16x32_bf16(Af[1][1], F1.v, aA1, 0, 0, 0);
    aA2 = __builtin_amdgcn_mfma_f32_16x16x32_bf16(Af[2][1], F1.v, aA2, 0, 0, 0);
    // ---- backward half: y = aB ∘ xb; issue E·y
    f32x4 y0 = aB0 * xb0;
    f32x4 y1 = aB1 * xb1;
    f32x4 y2 = aB2 * xb2;
    if (rn) RENORM3(y0, y1, y2);
    union { uint32_t u[4]; bf16x8 v; } G0, G1;
    G0.u[0] = pk2(y0.x, y0.y);
    G0.u[1] = pk2(y0.z, y0.w);
    G0.u[2] = pk2(y1.x, y1.y);
    G0.u[3] = pk2(y1.z, y1.w);
    G1.u[0] = pk2(y2.x, y2.y);
    G1.u[1] = pk2(y2.z, y2.w);
    G1.u[2] = 0u;
    G1.u[3] = 0u;
    aB0 = __builtin_amdgcn_mfma_f32_16x16x32_bf16(Ab[0][0], G0.v, z4, 0, 0, 0);
    aB1 = __builtin_amdgcn_mfma_f32_16x16x32_bf16(Ab[1][0], G0.v, z4, 0, 0, 0);
    aB2 = __builtin_amdgcn_mfma_f32_16x16x32_bf16(Ab[2][0], G0.v, z4, 0, 0, 0);
    aB0 = __builtin_amdgcn_mfma_f32_16x16x32_bf16(Ab[0][1], G1.v, aB0, 0, 0, 0);
    aB1 = __builtin_amdgcn_mfma_f32_16x16x32_bf16(Ab[1][1], G1.v, aB1, 0, 0, 0);
    aB2 = __builtin_amdgcn_mfma_f32_16x16x32_bf16(Ab[2][1], G1.v, aB2, 0, 0, 0);
  };

  const int m = len >> 1;
  const int nwin = (m + 31) >> 5;

  // stage window 0: fwd rows [0,32), bwd rows [len-32, len)
#pragma unroll
  for (int k = 0; k < 6; ++k) {
    gload16(embase + k * 256 + lane * 4, &fbuf[0][k * 256]);
    gload16(embase + (size_t)(len - 32) * NT + k * 256 + lane * 4,
            &bbuf[0][k * 256]);
  }

  for (int c = 0; c < nwin; ++c) {
    asm volatile("s_waitcnt vmcnt(0)" ::: "memory");
    if (c + 1 < nwin) {
      const float* fsrc = embase + (size_t)(32 * (c + 1)) * NT;
      const float* bsrc = embase + (size_t)(len - 32 - 32 * (c + 1)) * NT;
#pragma unroll
      for (int k = 0; k < 6; ++k) {
        gload16(fsrc + k * 256 + lane * 4, &fbuf[(c + 1) & 1][k * 256]);
        gload16(bsrc + k * 256 + lane * 4, &bbuf[(c + 1) & 1][k * 256]);
      }
    }
    float* F = fbuf[c & 1];
    float* Bw = bbuf[c & 1];
#pragma unroll
    for (int r = 0; r < 6; ++r) {  // pre-exp, flat (2-way alias = free)
      f32x4* p = (f32x4*)(F + r * 256 + lane * 4);
      f32x4 vx = *p;
      vx.x = __expf(vx.x);
      vx.y = __expf(vx.y);
      vx.z = __expf(vx.z);
      vx.w = __expf(vx.w);
      *p = vx;
      f32x4* p2 = (f32x4*)(Bw + r * 256 + lane * 4);
      f32x4 vy = *p2;
      vy.x = __expf(vy.x);
      vy.y = __expf(vy.y);
      vy.z = __expf(vy.z);
      vy.w = __expf(vy.w);
      *p2 = vy;
    }
    const int pairs = (m - 32 * c < 32) ? (m - 32 * c) : 32;
    // 1-pair-lookahead register pipeline (named A/B sets, static indexing)
    f32x4 XF0a, XF1a, XF2a, XB0a, XB1a, XB2a;
    f32x4 XF0b, XF1b, XF2b, XB0b, XB1b, XB2b;
    LOADX(a, 0);
    int s = 0;
    for (; s + 2 <= pairs; s += 2) {
      LOADX(b, s + 1);  // prefetch pair s+1 while computing pair s
      pairbody(XF0a, XF1a, XF2a, XB0a, XB1a, XB2a,
               ((s & 7) == 7) || (s == pairs - 1));
      if (s + 2 < pairs) LOADX(a, s + 2);  // prefetch pair s+2
      pairbody(XF0b, XF1b, XF2b, XB0b, XB1b, XB2b,
               (((s + 1) & 7) == 7) || (s + 1 == pairs - 1));
    }
    if (s < pairs)  // odd tail: pair already loaded in A set
      pairbody(XF0a, XF1a, XF2a, XB0a, XB1a, XB2a, true);
  }

  if (len & 1) {  // one extra backward step, row m, direct from global
    const float* rp = embase + (size_t)m * NT;
    f32x4 xb0 = *(const f32x4*)(rp + 4 * g);
    f32x4 xb1 = *(const f32x4*)(rp + 16 + 4 * g);
    f32x4 xb2 = *(const f32x4*)(rp + 32 + 4 * g);
#define EXP4(v) \
  v.x = __expf(v.x); v.y = __expf(v.y); v.z = __expf(v.z); v.w = __expf(v.w)
    EXP4(xb0);
    EXP4(xb1);
    EXP4(xb2);
#undef EXP4
    const f32x4 y0 = aB0 * xb0, y1 = aB1 * xb1, y2 = aB2 * xb2;
    union { uint32_t u[4]; bf16x8 v; } G0, G1;
    G0.u[0] = pk2(y0.x, y0.y);
    G0.u[1] = pk2(y0.z, y0.w);
    G0.u[2] = pk2(y1.x, y1.y);
    G0.u[3] = pk2(y1.z, y1.w);
    G1.u[0] = pk2(y2.x, y2.y);
    G1.u[1] = pk2(y2.z, y2.w);
    G1.u[2] = 0u;
    G1.u[3] = 0u;
    aB0 = __builtin_amdgcn_mfma_f32_16x16x32_bf16(Ab[0][0], G0.v, z4, 0, 0, 0);
    aB1 = __builtin_amdgcn_mfma_f32_16x16x32_bf16(Ab[1][0], G0.v, z4, 0, 0, 0);
    aB2 = __builtin_amdgcn_mfma_f32_16x16x32_bf16(Ab[2][0], G0.v, z4, 0, 0, 0);
    aB0 = __builtin_amdgcn_mfma_f32_16x16x32_bf16(Ab[0][1], G1.v, aB0, 0, 0, 0);
    aB1 = __builtin_amdgcn_mfma_f32_16x16x32_bf16(Ab[1][1], G1.v, aB1, 0, 0, 0);
    aB2 = __builtin_amdgcn_mfma_f32_16x16x32_bf16(Ab[2][1], G1.v, aB2, 0, 0, 0);
  }

  // Z = q_m · w_m. vf = q_m (renormed at last pair); aB = w_m in flight.
  f32x4 dv = vf0 * aB0 + vf1 * aB1 + vf2 * aB2;
  float dsum = (dv.x + dv.y) + (dv.z + dv.w);
#pragma unroll
  for (int d = 32; d >= 1; d >>= 1) dsum += __shfl_xor(dsum, d);
  const float logZ =
      __logf(dsum) + (float)cbits * 0.69314718055994531f + Tr[TAG_STOP * NT];

  // gold score (matched at absmax 0 since R2)
  const int* trow = tags + (size_t)b * SLEN;
  float gsc = 0.f;
  for (int t = lane; t < len; t += 64) {
    const int tag = trow[t];
    const int prev = (t == 0) ? TAG_START : trow[t - 1];
    gsc += Tr[tag * NT + prev] + embase[(size_t)t * NT + tag];
  }
#pragma unroll
  for (int d = 32; d >= 1; d >>= 1) gsc += __shfl_xor(gsc, d);

  if (lane == 0) {
    const int last = trow[len - 1];
    ws[b] = logZ - (gsc + Tr[TAG_STOP * NT + last]);
  }
}

// Deterministic tree-mean over B values (no atomics).
__global__ void crf_reduce_kernel(const float* __restrict__ wsrc,
                                  float* __restrict__ out, int n) {
  const int tid = threadIdx.x;
  float v = (tid < n) ? wsrc[tid] : 0.f;
#pragma unroll
  for (int d = 32; d >= 1; d >>= 1) v += __shfl_xor(v, d);
  __shared__ float part[16];
  if ((tid & 63) == 0) part[tid >> 6] = v;
  __syncthreads();
  if (tid == 0) {
    float s = 0.f;
    for (int i = 0; i < 16; ++i) s += part[i];
    out[0] = s / (float)n;
  }
}

extern "C" void kernel_launch(void* const* d_in, const int* in_sizes, int n_in,
                              void* d_out, int out_size, void* d_ws, size_t ws_size,
                              hipStream_t stream) {
  const float* em = (const float*)d_in[0];
  const int* tags = (const int*)d_in[1];
  const int* mask = (const int*)d_in[2];
  const float* Tr = (const float*)d_in[3];
  const int B = in_sizes[0] / (SLEN * NT);  // 1024

  float* ws = (float*)d_ws;  // B floats
  crf_fwd_kernel<<<B, 64, 0, stream>>>(em, tags, mask, Tr, ws);
  crf_reduce_kernel<<<1, 1024, 0, stream>>>(ws, (float*)d_out, B);
}